// Round 4
// baseline (31.652 us; speedup 1.0000x reference)
//
#include <hip/hip_runtime.h>
#include <math.h>

#define IMG    512
#define IMG2   (IMG*IMG)
#define TC     64
#define TR     32
#define ECC    72              // TC + 8 extended columns
#define PITCH  33              // entries per column (TR + 1 pad)
#define LDSN   (ECC*PITCH)     // 2376 x 16B = 38,016 B
#define NBATCH 32
#define NBLOCKS ((IMG/TC)*(IMG/TR)*NBATCH)   // 8*16*32 = 4096
#define NPIX   8388608.0f

typedef float f2 __attribute__((ext_vector_type(2)));
typedef float f4 __attribute__((ext_vector_type(4)));

// RNE pack two f32 -> {lo16=bf16(a), hi16=bf16(b)} as float bit-pattern.
__device__ __forceinline__ float pk_bf16(float a, float b) {
    float r;
    asm("v_cvt_pk_bf16_f32 %0, %1, %2" : "=v"(r) : "v"(a), "v"(b));
    return r;
}

// row -> swizzled row: XOR low 2 bits with (row>>3); bijective within 8-row octets,
// spreads the 16B-stride transposed layout across bank groups (4-way -> conflict-free).
__device__ __forceinline__ int swz(int row) { return row ^ ((row >> 3) & 3); }

__global__ __launch_bounds__(256, 4)
void lncc_main(const float* __restrict__ Tm, const float* __restrict__ Im,
               float* __restrict__ partial)
{
    __shared__ f4 V[LDSN];              // {w0, w1, pk(w2,w3), pk(w4,w4)}
    __shared__ float wsum[4];

    const int tid = threadIdx.x;
    const int x0 = blockIdx.x * TC;
    const int y0 = blockIdx.y * TR;
    const size_t base = (size_t)blockIdx.z * IMG2;
    const float* tb = Tm + base;
    const float* ib = Im + base;

    const bool interior = (blockIdx.x >= 1) & (blockIdx.x <= 6) &
                          (blockIdx.y >= 1) & (blockIdx.y <= 14);

    // ---------------- Pass 1: vertical sliding 9-sums ----------------
    if (interior) {
        // 72 threads x 2 columns each, f2 loads, packed-f32 accumulation.
        if (tid < 72) {
            const int pr    = tid % 36;        // column pair index
            const int strip = tid / 36;        // 0,1 -> rows [0,16) / [16,32)
            const int r0    = strip * 16;
            const int c2    = pr * 2;          // first extended column of pair
            const int off0  = (y0 + r0 - 4) * IMG + (x0 + c2 - 4);
            const float* tp = tb + off0;
            const float* ip = ib + off0;

            f2 rt[9], rv[9];
            f2 s0 = {0.f,0.f}, s1 = {0.f,0.f}, s2 = {0.f,0.f},
               s3 = {0.f,0.f}, s4 = {0.f,0.f};

            #pragma unroll
            for (int j = 0; j < 24; ++j) {
                const f2 t = *(const f2*)(tp + j * IMG);
                const f2 v = *(const f2*)(ip + j * IMG);
                s0 += t; s1 += v;
                s2 += t * t; s3 += v * v; s4 += t * v;
                rt[j % 9] = t; rv[j % 9] = v;
                if (j >= 8) {
                    const int k   = j - 8;
                    const int row = r0 + k;
                    f4 e0, e1;
                    e0.x = s0.x; e0.y = s1.x;
                    e0.z = pk_bf16(s2.x, s3.x); e0.w = pk_bf16(s4.x, s4.x);
                    e1.x = s0.y; e1.y = s1.y;
                    e1.z = pk_bf16(s2.y, s3.y); e1.w = pk_bf16(s4.y, s4.y);
                    const int rw = swz(row);   // compile-time per unrolled iter
                    V[c2 * PITCH + rw]       = e0;
                    V[(c2 + 1) * PITCH + rw] = e1;
                    const f2 ot = rt[k % 9], ov = rv[k % 9];
                    s0 -= ot; s1 -= ov;
                    s2 -= ot * ot; s3 -= ov * ov; s4 -= ot * ov;
                }
            }
        }
    } else {
        // Border blocks: scalar path with clamp + multiplicative mask (R3-proven).
        if (tid < 144) {
            const int ec    = tid % ECC;
            const int strip = tid / ECC;
            const int r0    = strip * 16;
            const int gx    = x0 + ec - 4;
            const float xm  = ((unsigned)gx < IMG) ? 1.0f : 0.0f;
            const int gxc   = gx < 0 ? 0 : (gx > IMG - 1 ? IMG - 1 : gx);
            const int Y     = y0 + r0 - 4;

            f2 ring[9];
            f2 w01 = {0.f,0.f}, w23 = {0.f,0.f};
            float w4 = 0.f;

            #pragma unroll
            for (int j = 0; j < 24; ++j) {
                const int gy  = Y + j;
                const float m = ((unsigned)gy < IMG) ? xm : 0.0f;
                const int gyc = gy < 0 ? 0 : (gy > IMG - 1 ? IMG - 1 : gy);
                const int off = (gyc << 9) + gxc;
                f2 tv;
                tv.x = tb[off] * m;
                tv.y = ib[off] * m;
                w01 += tv;
                w23 += tv * tv;
                w4  = fmaf(tv.x, tv.y, w4);
                ring[j % 9] = tv;
                if (j >= 8) {
                    const int k = j - 8;
                    f4 e;
                    e.x = w01.x; e.y = w01.y;
                    e.z = pk_bf16(w23.x, w23.y);
                    e.w = pk_bf16(w4, w4);
                    V[ec * PITCH + swz(r0 + k)] = e;
                    const f2 o = ring[k % 9];
                    w01 -= o;
                    w23 -= o * o;
                    w4  = fmaf(-o.x, o.y, w4);
                }
            }
        }
    }
    __syncthreads();

    // ------------- Pass 2: horizontal sliding 9-sums + score -------------
    float lsum = 0.f;
    {
        const int row  = tid & 31;
        const int cb   = (tid >> 5) * 8;
        const f4* src  = &V[cb * PITCH + swz(row)];   // then src[k*PITCH]

        f2 r01[9], r23[9];
        float r4[9];
        f2 W01 = {0.f,0.f}, W23 = {0.f,0.f};
        float W4 = 0.f;
        const float inv81 = 1.0f / 81.0f;

        #pragma unroll
        for (int k = 0; k < 16; ++k) {
            const f4 e = src[k * PITCH];              // conflict-free after swizzle
            const unsigned u23 = __float_as_uint(e.z);
            const unsigned u4  = __float_as_uint(e.w);
            f2 h01; h01.x = e.x; h01.y = e.y;
            f2 h23;
            h23.x = __uint_as_float(u23 << 16);
            h23.y = __uint_as_float(u23 & 0xffff0000u);
            const float h4 = __uint_as_float(u4 & 0xffff0000u);
            W01 += h01; W23 += h23; W4 += h4;
            const int ri = k % 9;
            r01[ri] = h01; r23[ri] = h23; r4[ri] = h4;
            if (k >= 8) {
                const float t0 = W01.x * inv81;
                const float t1 = W01.y * inv81;
                const float cross = fmaf(-t0, W01.y, W4);
                const float Iv    = fmaf(-t0, W01.x, W23.x);
                const float Jv    = fmaf(-t1, W01.y, W23.y);
                const float den   = fmaf(Iv, Jv, 1e-12f);
                lsum += cross * __builtin_amdgcn_rsqf(den);
                const int o = (k - 8) % 9;
                W01 -= r01[o]; W23 -= r23[o]; W4 -= r4[o];
            }
        }
    }

    // ---------------- deterministic block reduction ----------------
    #pragma unroll
    for (int d = 32; d >= 1; d >>= 1) lsum += __shfl_down(lsum, d, 64);
    if ((tid & 63) == 0) wsum[tid >> 6] = lsum;
    __syncthreads();
    if (tid == 0) {
        const int bid = (blockIdx.z * gridDim.y + blockIdx.y) * gridDim.x + blockIdx.x;
        partial[bid] = wsum[0] + wsum[1] + wsum[2] + wsum[3];
    }
}

__global__ __launch_bounds__(256)
void lncc_reduce(const float* __restrict__ partial, float* __restrict__ out)
{
    __shared__ float ws[4];
    const int tid = threadIdx.x;
    float s = 0.f;
    #pragma unroll
    for (int i = 0; i < NBLOCKS / 256; ++i) s += partial[tid + i * 256];
    #pragma unroll
    for (int d = 32; d >= 1; d >>= 1) s += __shfl_down(s, d, 64);
    if ((tid & 63) == 0) ws[tid >> 6] = s;
    __syncthreads();
    if (tid == 0) out[0] = 1.0f - (ws[0] + ws[1] + ws[2] + ws[3]) / NPIX;
}

extern "C" void kernel_launch(void* const* d_in, const int* in_sizes, int n_in,
                              void* d_out, int out_size, void* d_ws, size_t ws_size,
                              hipStream_t stream)
{
    (void)in_sizes; (void)n_in; (void)out_size; (void)ws_size;
    const float* Tm = (const float*)d_in[0];   // template
    const float* Im = (const float*)d_in[1];   // image
    float* out  = (float*)d_out;
    float* part = (float*)d_ws;                // NBLOCKS floats of scratch

    dim3 grid(IMG / TC, IMG / TR, NBATCH);     // (8, 16, 32)
    lncc_main<<<grid, 256, 0, stream>>>(Tm, Im, part);
    lncc_reduce<<<1, 256, 0, stream>>>(part, out);
}

// Round 5
// 27.681 us; speedup vs baseline: 1.1434x; 1.1434x over previous
//
#include <hip/hip_runtime.h>
#include <math.h>

#define IMG    512
#define IMG2   (IMG*IMG)
#define TC     64
#define TR     32
#define ECC    72              // TC + 8 extended columns
#define PITCH  33              // rows per column incl. dump row 32
#define NBATCH 32
#define NBLOCKS ((IMG/TC)*(IMG/TR)*NBATCH)   // 4096
#define NPIX   8388608.0f

typedef unsigned int u32;

// RNE pack: dst.lo16 = bf16(a), dst.hi16 = bf16(b)
__device__ __forceinline__ u32 pk_bf16(float a, float b) {
    float r;
    asm("v_cvt_pk_bf16_f32 %0, %1, %2" : "=v"(r) : "v"(a), "v"(b));
    return __float_as_uint(r);
}

__global__ __launch_bounds__(256, 5)
void lncc_main(const float* __restrict__ Tm, const float* __restrict__ Im,
               float* __restrict__ partial)
{
    // 12 B/entry column sums, split so pass-2 column reads are conflict-free:
    //   AB: uint2 {pk(w0,w1), pk(w2,w3)}  bank = 2*(ec+row) mod 32 -> 2-way (free)
    //   Cc: u32   pk(w4,w4)               bank = (ec+row) mod 32   -> conflict-free
    __shared__ uint2 AB[ECC * PITCH];      // 19,008 B
    __shared__ u32   Cc[ECC * PITCH];      //  9,504 B
    __shared__ float wsum[4];

    const int tid = threadIdx.x;
    const int x0 = blockIdx.x * TC;
    const int y0 = blockIdx.y * TR;
    const size_t base = (size_t)blockIdx.z * IMG2;
    const float* tb = Tm + base;
    const float* ib = Im + base;

    const bool interior = (blockIdx.x - 1u < 6u) & (blockIdx.y - 1u < 14u);

    // ---- Pass 1: vertical sliding 9-sums; 3 strips x 72 columns, 19 iters ----
    if (tid < 3 * ECC) {
        const int ec    = tid % ECC;
        const int strip = tid / ECC;        // 0,1,2
        const int r0    = strip * 11;       // strip2 writes row 32 = dump slot

        float rt[9], rv[9];
        float s0 = 0.f, s1 = 0.f, s2 = 0.f, s3 = 0.f, s4 = 0.f;

        if (interior) {
            const int off0 = (y0 + r0 - 4) * IMG + (x0 + ec - 4);
            const float* tp = tb + off0;
            const float* ip = ib + off0;
            #pragma unroll
            for (int j = 0; j < 19; ++j) {
                const float t = tp[j * IMG];
                const float v = ip[j * IMG];
                s0 += t; s1 += v;
                s2 = fmaf(t, t, s2); s3 = fmaf(v, v, s3); s4 = fmaf(t, v, s4);
                rt[j % 9] = t; rv[j % 9] = v;
                if (j >= 8) {
                    const int idx = ec * PITCH + r0 + (j - 8);
                    AB[idx] = make_uint2(pk_bf16(s0, s1), pk_bf16(s2, s3));
                    Cc[idx] = pk_bf16(s4, s4);
                    const float ot = rt[(j - 8) % 9], ov = rv[(j - 8) % 9];
                    s0 -= ot; s1 -= ov;
                    s2 = fmaf(-ot, ot, s2); s3 = fmaf(-ov, ov, s3); s4 = fmaf(-ot, ov, s4);
                }
            }
        } else {
            const int gx   = x0 + ec - 4;
            const float xm = ((unsigned)gx < IMG) ? 1.0f : 0.0f;
            const int gxc  = gx < 0 ? 0 : (gx > IMG - 1 ? IMG - 1 : gx);
            const int Y    = y0 + r0 - 4;
            #pragma unroll
            for (int j = 0; j < 19; ++j) {
                const int gy  = Y + j;
                const float m = ((unsigned)gy < IMG) ? xm : 0.0f;
                const int gyc = gy < 0 ? 0 : (gy > IMG - 1 ? IMG - 1 : gy);
                const int off = (gyc << 9) + gxc;
                const float t = tb[off] * m;
                const float v = ib[off] * m;
                s0 += t; s1 += v;
                s2 = fmaf(t, t, s2); s3 = fmaf(v, v, s3); s4 = fmaf(t, v, s4);
                rt[j % 9] = t; rv[j % 9] = v;
                if (j >= 8) {
                    const int idx = ec * PITCH + r0 + (j - 8);
                    AB[idx] = make_uint2(pk_bf16(s0, s1), pk_bf16(s2, s3));
                    Cc[idx] = pk_bf16(s4, s4);
                    const float ot = rt[(j - 8) % 9], ov = rv[(j - 8) % 9];
                    s0 -= ot; s1 -= ov;
                    s2 = fmaf(-ot, ot, s2); s3 = fmaf(-ov, ov, s3); s4 = fmaf(-ot, ov, s4);
                }
            }
        }
    }
    __syncthreads();

    // ---- Pass 2: horizontal sliding 9-sums + score; 32 rows x 8 segments ----
    float lsum = 0.f;
    {
        const int row = tid & 31;
        const int b0  = (tid >> 5) * 8 * PITCH + row;
        float W0 = 0.f, W1 = 0.f, W2 = 0.f, W3 = 0.f, W4 = 0.f;
        uint2 rab[9];
        u32   rc[9];
        const float inv81 = 1.0f / 81.0f;

        #pragma unroll
        for (int k = 0; k < 16; ++k) {
            const uint2 ab = AB[b0 + k * PITCH];
            const u32   c  = Cc[b0 + k * PITCH];
            W0 += __uint_as_float(ab.x << 16);
            W1 += __uint_as_float(ab.x & 0xffff0000u);
            W2 += __uint_as_float(ab.y << 16);
            W3 += __uint_as_float(ab.y & 0xffff0000u);
            W4 += __uint_as_float(c & 0xffff0000u);
            rab[k % 9] = ab; rc[k % 9] = c;
            if (k >= 8) {
                const float t0 = W0 * inv81;
                const float t1 = W1 * inv81;
                const float cross = fmaf(-t0, W1, W4);
                const float Iv    = fmaf(-t0, W0, W2);
                const float Jv    = fmaf(-t1, W1, W3);
                const float den   = fmaf(Iv, Jv, 1e-12f);
                lsum += cross * __builtin_amdgcn_rsqf(den);
                const uint2 oab = rab[(k - 8) % 9];
                const u32   oc  = rc[(k - 8) % 9];
                W0 -= __uint_as_float(oab.x << 16);
                W1 -= __uint_as_float(oab.x & 0xffff0000u);
                W2 -= __uint_as_float(oab.y << 16);
                W3 -= __uint_as_float(oab.y & 0xffff0000u);
                W4 -= __uint_as_float(oc & 0xffff0000u);
            }
        }
    }

    // ---- deterministic block reduction ----
    #pragma unroll
    for (int d = 32; d >= 1; d >>= 1) lsum += __shfl_down(lsum, d, 64);
    if ((tid & 63) == 0) wsum[tid >> 6] = lsum;
    __syncthreads();
    if (tid == 0) {
        const int bid = (blockIdx.z * gridDim.y + blockIdx.y) * gridDim.x + blockIdx.x;
        partial[bid] = wsum[0] + wsum[1] + wsum[2] + wsum[3];
    }
}

__global__ __launch_bounds__(256)
void lncc_reduce(const float* __restrict__ partial, float* __restrict__ out)
{
    __shared__ float ws[4];
    const int tid = threadIdx.x;
    float s = 0.f;
    #pragma unroll
    for (int i = 0; i < NBLOCKS / 256; ++i) s += partial[tid + i * 256];
    #pragma unroll
    for (int d = 32; d >= 1; d >>= 1) s += __shfl_down(s, d, 64);
    if ((tid & 63) == 0) ws[tid >> 6] = s;
    __syncthreads();
    if (tid == 0) out[0] = 1.0f - (ws[0] + ws[1] + ws[2] + ws[3]) / NPIX;
}

extern "C" void kernel_launch(void* const* d_in, const int* in_sizes, int n_in,
                              void* d_out, int out_size, void* d_ws, size_t ws_size,
                              hipStream_t stream)
{
    (void)in_sizes; (void)n_in; (void)out_size; (void)ws_size;
    const float* Tm = (const float*)d_in[0];   // template
    const float* Im = (const float*)d_in[1];   // image
    float* out  = (float*)d_out;
    float* part = (float*)d_ws;                // NBLOCKS floats of scratch

    dim3 grid(IMG / TC, IMG / TR, NBATCH);     // (8, 16, 32)
    lncc_main<<<grid, 256, 0, stream>>>(Tm, Im, part);
    lncc_reduce<<<1, 256, 0, stream>>>(part, out);
}